// Round 7
// baseline (254.043 us; speedup 1.0000x reference)
//
#include <hip/hip_runtime.h>

#define N_NODES 50000
#define N_EDGES 800000
#define DIM 64
#define NUM_GRAPHS 64
#define NPART 8
#define PART_NODES 6250   // N_NODES / NPART exactly

// ---- degree count, XCD-partitioned: partition p owns dst range, so cnt
// lines are written from a single XCD (no cross-XCD line bouncing) ----
__global__ void count_deg_kernel(const int* __restrict__ dst, int* __restrict__ cnt, int E) {
  int p = blockIdx.x & 7;
  int lo = p * PART_NODES, hi = lo + PART_NODES;
  int stride = (gridDim.x >> 3) * blockDim.x;
  for (int e = (blockIdx.x >> 3) * blockDim.x + threadIdx.x; e < E; e += stride) {
    int d = dst[e];
    if (d >= lo && d < hi) atomicAdd(&cnt[d], 1);
  }
}

// ---- scan phase A: block-local exclusive scan of cnt, block sums, fused dis ----
__global__ void scanA_kernel(const int* __restrict__ cnt, int* __restrict__ rowptr,
                             int* __restrict__ bsum, float* __restrict__ dis, int N) {
  __shared__ int wsum[16];
  int i = blockIdx.x * 1024 + threadIdx.x;
  int lane = threadIdx.x & 63, wid = threadIdx.x >> 6;
  int v = (i < N) ? cnt[i] : 0;
  if (i < N) dis[i] = rsqrtf((float)(v + 1));
  int sv = v;
  #pragma unroll
  for (int off = 1; off < 64; off <<= 1) {
    int t = __shfl_up(sv, off, 64);
    if (lane >= off) sv += t;
  }
  if (lane == 63) wsum[wid] = sv;
  __syncthreads();
  if (wid == 0) {
    int wv = (lane < 16) ? wsum[lane] : 0;
    #pragma unroll
    for (int off = 1; off < 16; off <<= 1) {
      int t = __shfl_up(wv, off, 64);
      if (lane >= off) wv += t;
    }
    if (lane < 16) wsum[lane] = wv;
  }
  __syncthreads();
  if (i < N) rowptr[i] = (wid ? wsum[wid - 1] : 0) + (sv - v);
  if (threadIdx.x == 1023) bsum[blockIdx.x] = wsum[15];
}

// ---- scan phase B: scan the (<=64) block sums; set rowptr[N] ----
__global__ void scanB_kernel(int* __restrict__ bsum, int* __restrict__ rowptr, int nb, int N) {
  int t = threadIdx.x;
  int v = (t < nb) ? bsum[t] : 0;
  #pragma unroll
  for (int off = 1; off < 64; off <<= 1) {
    int u = __shfl_up(v, off, 64);
    if (t >= off) v += u;
  }
  if (t < nb) bsum[t] = v;
  if (t == nb - 1) rowptr[N] = v;
}

// ---- scan phase C: add block offsets; also write cursor copy ----
__global__ void scanC_kernel(int* __restrict__ rowptr, const int* __restrict__ bsum,
                             int* __restrict__ cursor, int N) {
  int b = blockIdx.x;
  int i = b * 1024 + threadIdx.x;
  if (i < N) {
    int off = b ? bsum[b - 1] : 0;
    int r = rowptr[i] + off;
    rowptr[i] = r;
    cursor[i] = r;
  }
}

// ---- fill CSR, XCD-partitioned; stores (src, dis[src]) pairs so the
// aggregate kernel has a single dependent load hop per edge ----
__global__ void fill_kernel(const int* __restrict__ src, const int* __restrict__ dst,
                            const float* __restrict__ dis,
                            int* __restrict__ cursor, int2* __restrict__ epair, int E) {
  int p = blockIdx.x & 7;
  int lo = p * PART_NODES, hi = lo + PART_NODES;
  int stride = (gridDim.x >> 3) * blockDim.x;
  for (int e = (blockIdx.x >> 3) * blockDim.x + threadIdx.x; e < E; e += stride) {
    int d = dst[e];
    if (d >= lo && d < hi) {
      int s = src[e];
      int pos = atomicAdd(&cursor[d], 1);
      epair[pos] = make_int2(s, __float_as_int(dis[s]));
    }
  }
}

// ---- aggregate: A_i = dis_i * ( sum_{j in in(i)} dis_j * F_j  +  dis_i * F_i ) ----
// one wave per node; 16-lane float4 groups x 4 edge slots, 16 edges/iter
__global__ __launch_bounds__(256) void aggregate_kernel(const float* __restrict__ F,
    const int* __restrict__ rowptr, const int2* __restrict__ epair,
    const float* __restrict__ dis, float* __restrict__ A, int N) {
  int node = blockIdx.x * 4 + (threadIdx.x >> 6);
  if (node >= N) return;
  int lane = threadIdx.x & 63;
  int qc = lane & 15;   // float4 column index within row
  int qe = lane >> 4;   // edge slot 0..3
  const float4* __restrict__ F4 = reinterpret_cast<const float4*>(F);
  int beg = rowptr[node], end = rowptr[node + 1];
  float ax = 0.f, ay = 0.f, az = 0.f, aw = 0.f;
  int j = beg;
  for (; j + 16 <= end; j += 16) {
    int2 p0 = epair[j + qe];
    int2 p1 = epair[j + 4 + qe];
    int2 p2 = epair[j + 8 + qe];
    int2 p3 = epair[j + 12 + qe];
    float4 v0 = F4[(size_t)p0.x * 16 + qc];
    float4 v1 = F4[(size_t)p1.x * 16 + qc];
    float4 v2 = F4[(size_t)p2.x * 16 + qc];
    float4 v3 = F4[(size_t)p3.x * 16 + qc];
    float d0 = __int_as_float(p0.y), d1 = __int_as_float(p1.y);
    float d2 = __int_as_float(p2.y), d3 = __int_as_float(p3.y);
    ax = fmaf(v0.x, d0, ax); ay = fmaf(v0.y, d0, ay);
    az = fmaf(v0.z, d0, az); aw = fmaf(v0.w, d0, aw);
    ax = fmaf(v1.x, d1, ax); ay = fmaf(v1.y, d1, ay);
    az = fmaf(v1.z, d1, az); aw = fmaf(v1.w, d1, aw);
    ax = fmaf(v2.x, d2, ax); ay = fmaf(v2.y, d2, ay);
    az = fmaf(v2.z, d2, az); aw = fmaf(v2.w, d2, aw);
    ax = fmaf(v3.x, d3, ax); ay = fmaf(v3.y, d3, ay);
    az = fmaf(v3.z, d3, az); aw = fmaf(v3.w, d3, aw);
  }
  if (j + 8 <= end) {
    int2 p0 = epair[j + qe];
    int2 p1 = epair[j + 4 + qe];
    float4 v0 = F4[(size_t)p0.x * 16 + qc];
    float4 v1 = F4[(size_t)p1.x * 16 + qc];
    float d0 = __int_as_float(p0.y), d1 = __int_as_float(p1.y);
    ax = fmaf(v0.x, d0, ax); ay = fmaf(v0.y, d0, ay);
    az = fmaf(v0.z, d0, az); aw = fmaf(v0.w, d0, aw);
    ax = fmaf(v1.x, d1, ax); ay = fmaf(v1.y, d1, ay);
    az = fmaf(v1.z, d1, az); aw = fmaf(v1.w, d1, aw);
    j += 8;
  }
  if (j + 4 <= end) {
    int2 p0 = epair[j + qe];
    float4 v0 = F4[(size_t)p0.x * 16 + qc];
    float d0 = __int_as_float(p0.y);
    ax = fmaf(v0.x, d0, ax); ay = fmaf(v0.y, d0, ay);
    az = fmaf(v0.z, d0, az); aw = fmaf(v0.w, d0, aw);
    j += 4;
  }
  if (j + qe < end) {
    int2 p = epair[j + qe];
    float4 v = F4[(size_t)p.x * 16 + qc];
    float d = __int_as_float(p.y);
    ax = fmaf(v.x, d, ax); ay = fmaf(v.y, d, ay);
    az = fmaf(v.z, d, az); aw = fmaf(v.w, d, aw);
  }
  // reduce the 4 edge-slot groups (lanes differ in bits 4..5)
  ax += __shfl_xor(ax, 16, 64); ax += __shfl_xor(ax, 32, 64);
  ay += __shfl_xor(ay, 16, 64); ay += __shfl_xor(ay, 32, 64);
  az += __shfl_xor(az, 16, 64); az += __shfl_xor(az, 32, 64);
  aw += __shfl_xor(aw, 16, 64); aw += __shfl_xor(aw, 32, 64);
  if (qe == 0) {
    float dn = dis[node];
    float4 sf = F4[(size_t)node * 16 + qc];
    float4 r;
    r.x = (ax + sf.x * dn) * dn;
    r.y = (ay + sf.y * dn) * dn;
    r.z = (az + sf.z * dn) * dn;
    r.w = (aw + sf.w * dn) * dn;
    reinterpret_cast<float4*>(A)[(size_t)node * 16 + qc] = r;
  }
}

// ---- fused GEMM + bias + relu: F = relu(A @ W + b); 64 rows/block ----
__global__ __launch_bounds__(256) void gemm_bias_relu(const float* __restrict__ X,
    const float* __restrict__ W, const float* __restrict__ b,
    float* __restrict__ F, int N) {
  __shared__ float4 Xs[64][16];
  int col = threadIdx.x & 63, wid = threadIdx.x >> 6;
  float wreg[DIM];
  #pragma unroll
  for (int k = 0; k < DIM; ++k) wreg[k] = W[k * DIM + col];
  float bias = b[col];
  int row0 = blockIdx.x * 64;
  for (int i = threadIdx.x; i < 64 * 16; i += 256) {
    int r = i >> 4, c = i & 15;
    int gr = row0 + r;
    Xs[r][c] = (gr < N) ? reinterpret_cast<const float4*>(X)[(size_t)gr * 16 + c]
                        : make_float4(0.f, 0.f, 0.f, 0.f);
  }
  __syncthreads();
  for (int rr = 0; rr < 16; ++rr) {
    int lr = wid * 16 + rr;
    int row = row0 + lr;
    if (row >= N) break;   // uniform per wave
    float a0 = 0.f, a1 = 0.f, a2 = 0.f, a3 = 0.f;
    #pragma unroll
    for (int kk = 0; kk < 16; ++kk) {
      float4 xv = Xs[lr][kk];
      a0 = fmaf(xv.x, wreg[4 * kk + 0], a0);
      a1 = fmaf(xv.y, wreg[4 * kk + 1], a1);
      a2 = fmaf(xv.z, wreg[4 * kk + 2], a2);
      a3 = fmaf(xv.w, wreg[4 * kk + 3], a3);
    }
    float v = a0 + a1 + a2 + a3 + bias;
    F[(size_t)row * DIM + col] = fmaxf(v, 0.f);
  }
}

// ---- layer-3 fused: y = relu(A@W3+b3) . Wl, block-level graph partials ----
__global__ __launch_bounds__(256) void gemm_dot_kernel(const float* __restrict__ X,
    const float* __restrict__ W, const float* __restrict__ b, const float* __restrict__ Wl,
    const int* __restrict__ batch, float* __restrict__ partial, int N) {
  __shared__ float4 Xs[64][16];
  __shared__ float yv[64];
  __shared__ float gpart[NUM_GRAPHS];
  int col = threadIdx.x & 63, wid = threadIdx.x >> 6;
  float wreg[DIM];
  #pragma unroll
  for (int k = 0; k < DIM; ++k) wreg[k] = W[k * DIM + col];
  float bias = b[col];
  float wl = Wl[col];
  int row0 = blockIdx.x * 64;
  if (threadIdx.x < 64) { yv[threadIdx.x] = 0.f; gpart[threadIdx.x] = 0.f; }
  for (int i = threadIdx.x; i < 64 * 16; i += 256) {
    int r = i >> 4, c = i & 15;
    int gr = row0 + r;
    Xs[r][c] = (gr < N) ? reinterpret_cast<const float4*>(X)[(size_t)gr * 16 + c]
                        : make_float4(0.f, 0.f, 0.f, 0.f);
  }
  __syncthreads();
  for (int rr = 0; rr < 16; ++rr) {
    int lr = wid * 16 + rr;
    int row = row0 + lr;
    if (row >= N) break;   // uniform per wave
    float a0 = 0.f, a1 = 0.f, a2 = 0.f, a3 = 0.f;
    #pragma unroll
    for (int kk = 0; kk < 16; ++kk) {
      float4 xv = Xs[lr][kk];
      a0 = fmaf(xv.x, wreg[4 * kk + 0], a0);
      a1 = fmaf(xv.y, wreg[4 * kk + 1], a1);
      a2 = fmaf(xv.z, wreg[4 * kk + 2], a2);
      a3 = fmaf(xv.w, wreg[4 * kk + 3], a3);
    }
    float v = fmaxf(a0 + a1 + a2 + a3 + bias, 0.f);
    float y = v * wl;
    #pragma unroll
    for (int off = 32; off > 0; off >>= 1) y += __shfl_down(y, off, 64);
    if (col == 0) yv[lr] = y;
  }
  __syncthreads();
  if (threadIdx.x < 64) {
    int row = row0 + threadIdx.x;
    if (row < N) atomicAdd(&gpart[batch[row]], yv[threadIdx.x]);
  }
  __syncthreads();
  if (threadIdx.x < NUM_GRAPHS) {
    int glo = batch[row0];
    int ghi = batch[min(row0 + 63, N - 1)];
    int g = threadIdx.x;
    if (g >= glo && g <= ghi) atomicAdd(&partial[g], gpart[g]);
  }
}

// ---- finalize: out[g] = partial[g]/count_g + bl ----
__global__ void pool_final_kernel(const float* __restrict__ partial, const int* __restrict__ batch,
                                  const float* __restrict__ bl, float* __restrict__ out, int N) {
  int g = threadIdx.x;  // 64 threads
  int lo = 0, hi = N;
  while (lo < hi) { int m = (lo + hi) >> 1; if (batch[m] < g) lo = m + 1; else hi = m; }
  int start = lo;
  hi = N;
  while (lo < hi) { int m = (lo + hi) >> 1; if (batch[m] < g + 1) lo = m + 1; else hi = m; }
  float c = fmaxf((float)(lo - start), 1.f);
  out[g] = partial[g] / c + bl[0];
}

extern "C" void kernel_launch(void* const* d_in, const int* in_sizes, int n_in,
                              void* d_out, int out_size, void* d_ws, size_t ws_size,
                              hipStream_t stream) {
  const float* x     = (const float*)d_in[0];
  const int*   ei    = (const int*)d_in[1];   // int64 in reference, delivered as int32
  const int*   batch = (const int*)d_in[2];
  const float* W1 = (const float*)d_in[3];
  const float* b1 = (const float*)d_in[4];
  const float* W2 = (const float*)d_in[5];
  const float* b2 = (const float*)d_in[6];
  const float* W3 = (const float*)d_in[7];
  const float* b3 = (const float*)d_in[8];
  const float* Wl = (const float*)d_in[9];
  const float* bl = (const float*)d_in[10];
  float* out = (float*)d_out;

  const int* srcp = ei;
  const int* dstp = ei + N_EDGES;

  char* ws = (char*)d_ws;
  size_t off = 0;
  auto alloc = [&](size_t bytes) { void* p = ws + off; off += (bytes + 255) & ~(size_t)255; return p; };
  int*   cnt     = (int*)  alloc((size_t)N_NODES * 4);        // reused as cursor
  float* dis     = (float*)alloc((size_t)N_NODES * 4);
  int*   rowptr  = (int*)  alloc((size_t)(N_NODES + 1) * 4);
  int*   bsum    = (int*)  alloc(64 * 4);
  float* partial = (float*)alloc(NUM_GRAPHS * 4);
  int2*  epair   = (int2*) alloc((size_t)N_EDGES * 8);
  float* bufA    = (float*)alloc((size_t)N_NODES * DIM * 4);
  float* bufB    = (float*)alloc((size_t)N_NODES * DIM * 4);

  const int NB = (N_NODES + 1023) / 1024;  // 49

  // ---- CSR build (edge passes XCD-partitioned by dst range) ----
  hipMemsetAsync(cnt, 0, (size_t)N_NODES * 4, stream);
  count_deg_kernel<<<1024, 256, 0, stream>>>(dstp, cnt, N_EDGES);
  scanA_kernel<<<NB, 1024, 0, stream>>>(cnt, rowptr, bsum, dis, N_NODES);
  scanB_kernel<<<1, 64, 0, stream>>>(bsum, rowptr, NB, N_NODES);
  scanC_kernel<<<NB, 1024, 0, stream>>>(rowptr, bsum, cnt, N_NODES);
  fill_kernel<<<1024, 256, 0, stream>>>(srcp, dstp, dis, cnt, epair, N_EDGES);

  // ---- 3 GCN layers ----
  const int GB = (N_NODES + 63) / 64;  // 782
  aggregate_kernel<<<(N_NODES + 3) / 4, 256, 0, stream>>>(x, rowptr, epair, dis, bufA, N_NODES);
  gemm_bias_relu<<<GB, 256, 0, stream>>>(bufA, W1, b1, bufB, N_NODES);
  aggregate_kernel<<<(N_NODES + 3) / 4, 256, 0, stream>>>(bufB, rowptr, epair, dis, bufA, N_NODES);
  gemm_bias_relu<<<GB, 256, 0, stream>>>(bufA, W2, b2, bufB, N_NODES);
  aggregate_kernel<<<(N_NODES + 3) / 4, 256, 0, stream>>>(bufB, rowptr, epair, dis, bufA, N_NODES);
  hipMemsetAsync(partial, 0, NUM_GRAPHS * 4, stream);
  gemm_dot_kernel<<<GB, 256, 0, stream>>>(bufA, W3, b3, Wl, batch, partial, N_NODES);
  pool_final_kernel<<<1, 64, 0, stream>>>(partial, batch, bl, out, N_NODES);
}

// Round 8
// 253.780 us; speedup vs baseline: 1.0010x; 1.0010x over previous
//
#include <hip/hip_runtime.h>

#define N_NODES 50000
#define N_EDGES 800000
#define DIM 64
#define NUM_GRAPHS 64
#define NPART 8
#define PART_NODES 6250   // N_NODES / NPART exactly

// ---- zero cnt[N] and partial[G] in one cheap launch (replaces 2 memsets
// whose rocclr fill dispatches showed ~42us each under graph replay) ----
__global__ void zero_kernel(int* __restrict__ cnt, float* __restrict__ partial) {
  int i = blockIdx.x * blockDim.x + threadIdx.x;
  if (i < N_NODES) cnt[i] = 0;
  if (i < NUM_GRAPHS) partial[i] = 0.f;
}

// ---- degree count, XCD-partitioned: partition p owns dst range, so cnt
// lines are written from a single XCD (no cross-XCD line bouncing) ----
__global__ void count_deg_kernel(const int* __restrict__ dst, int* __restrict__ cnt, int E) {
  int p = blockIdx.x & 7;
  int lo = p * PART_NODES, hi = lo + PART_NODES;
  int stride = (gridDim.x >> 3) * blockDim.x;
  for (int e = (blockIdx.x >> 3) * blockDim.x + threadIdx.x; e < E; e += stride) {
    int d = dst[e];
    if (d >= lo && d < hi) atomicAdd(&cnt[d], 1);
  }
}

// ---- scan phase A: block-local exclusive scan of cnt, block sums, fused dis ----
__global__ void scanA_kernel(const int* __restrict__ cnt, int* __restrict__ rowptr,
                             int* __restrict__ bsum, float* __restrict__ dis, int N) {
  __shared__ int wsum[16];
  int i = blockIdx.x * 1024 + threadIdx.x;
  int lane = threadIdx.x & 63, wid = threadIdx.x >> 6;
  int v = (i < N) ? cnt[i] : 0;
  if (i < N) dis[i] = rsqrtf((float)(v + 1));
  int sv = v;
  #pragma unroll
  for (int off = 1; off < 64; off <<= 1) {
    int t = __shfl_up(sv, off, 64);
    if (lane >= off) sv += t;
  }
  if (lane == 63) wsum[wid] = sv;
  __syncthreads();
  if (wid == 0) {
    int wv = (lane < 16) ? wsum[lane] : 0;
    #pragma unroll
    for (int off = 1; off < 16; off <<= 1) {
      int t = __shfl_up(wv, off, 64);
      if (lane >= off) wv += t;
    }
    if (lane < 16) wsum[lane] = wv;
  }
  __syncthreads();
  if (i < N) rowptr[i] = (wid ? wsum[wid - 1] : 0) + (sv - v);
  if (threadIdx.x == 1023) bsum[blockIdx.x] = wsum[15];
}

// ---- scan phase B: scan the (<=64) block sums; set rowptr[N] ----
__global__ void scanB_kernel(int* __restrict__ bsum, int* __restrict__ rowptr, int nb, int N) {
  int t = threadIdx.x;
  int v = (t < nb) ? bsum[t] : 0;
  #pragma unroll
  for (int off = 1; off < 64; off <<= 1) {
    int u = __shfl_up(v, off, 64);
    if (t >= off) v += u;
  }
  if (t < nb) bsum[t] = v;
  if (t == nb - 1) rowptr[N] = v;
}

// ---- scan phase C: add block offsets; also write cursor copy ----
__global__ void scanC_kernel(int* __restrict__ rowptr, const int* __restrict__ bsum,
                             int* __restrict__ cursor, int N) {
  int b = blockIdx.x;
  int i = b * 1024 + threadIdx.x;
  if (i < N) {
    int off = b ? bsum[b - 1] : 0;
    int r = rowptr[i] + off;
    rowptr[i] = r;
    cursor[i] = r;
  }
}

// ---- fill CSR, XCD-partitioned; stores (src, dis[src]) pairs so the
// aggregate kernel has a single dependent load hop per edge ----
__global__ void fill_kernel(const int* __restrict__ src, const int* __restrict__ dst,
                            const float* __restrict__ dis,
                            int* __restrict__ cursor, int2* __restrict__ epair, int E) {
  int p = blockIdx.x & 7;
  int lo = p * PART_NODES, hi = lo + PART_NODES;
  int stride = (gridDim.x >> 3) * blockDim.x;
  for (int e = (blockIdx.x >> 3) * blockDim.x + threadIdx.x; e < E; e += stride) {
    int d = dst[e];
    if (d >= lo && d < hi) {
      int s = src[e];
      int pos = atomicAdd(&cursor[d], 1);
      epair[pos] = make_int2(s, __float_as_int(dis[s]));
    }
  }
}

// ---- aggregate: A_i = dis_i * ( sum_{j in in(i)} dis_j * F_j  +  dis_i * F_i ) ----
// one wave per node; 16-lane float4 groups x 4 edge slots, 16 edges/iter
__global__ __launch_bounds__(256) void aggregate_kernel(const float* __restrict__ F,
    const int* __restrict__ rowptr, const int2* __restrict__ epair,
    const float* __restrict__ dis, float* __restrict__ A, int N) {
  int node = blockIdx.x * 4 + (threadIdx.x >> 6);
  if (node >= N) return;
  int lane = threadIdx.x & 63;
  int qc = lane & 15;   // float4 column index within row
  int qe = lane >> 4;   // edge slot 0..3
  const float4* __restrict__ F4 = reinterpret_cast<const float4*>(F);
  int beg = rowptr[node], end = rowptr[node + 1];
  float ax = 0.f, ay = 0.f, az = 0.f, aw = 0.f;
  int j = beg;
  for (; j + 16 <= end; j += 16) {
    int2 p0 = epair[j + qe];
    int2 p1 = epair[j + 4 + qe];
    int2 p2 = epair[j + 8 + qe];
    int2 p3 = epair[j + 12 + qe];
    float4 v0 = F4[(size_t)p0.x * 16 + qc];
    float4 v1 = F4[(size_t)p1.x * 16 + qc];
    float4 v2 = F4[(size_t)p2.x * 16 + qc];
    float4 v3 = F4[(size_t)p3.x * 16 + qc];
    float d0 = __int_as_float(p0.y), d1 = __int_as_float(p1.y);
    float d2 = __int_as_float(p2.y), d3 = __int_as_float(p3.y);
    ax = fmaf(v0.x, d0, ax); ay = fmaf(v0.y, d0, ay);
    az = fmaf(v0.z, d0, az); aw = fmaf(v0.w, d0, aw);
    ax = fmaf(v1.x, d1, ax); ay = fmaf(v1.y, d1, ay);
    az = fmaf(v1.z, d1, az); aw = fmaf(v1.w, d1, aw);
    ax = fmaf(v2.x, d2, ax); ay = fmaf(v2.y, d2, ay);
    az = fmaf(v2.z, d2, az); aw = fmaf(v2.w, d2, aw);
    ax = fmaf(v3.x, d3, ax); ay = fmaf(v3.y, d3, ay);
    az = fmaf(v3.z, d3, az); aw = fmaf(v3.w, d3, aw);
  }
  if (j + 8 <= end) {
    int2 p0 = epair[j + qe];
    int2 p1 = epair[j + 4 + qe];
    float4 v0 = F4[(size_t)p0.x * 16 + qc];
    float4 v1 = F4[(size_t)p1.x * 16 + qc];
    float d0 = __int_as_float(p0.y), d1 = __int_as_float(p1.y);
    ax = fmaf(v0.x, d0, ax); ay = fmaf(v0.y, d0, ay);
    az = fmaf(v0.z, d0, az); aw = fmaf(v0.w, d0, aw);
    ax = fmaf(v1.x, d1, ax); ay = fmaf(v1.y, d1, ay);
    az = fmaf(v1.z, d1, az); aw = fmaf(v1.w, d1, aw);
    j += 8;
  }
  if (j + 4 <= end) {
    int2 p0 = epair[j + qe];
    float4 v0 = F4[(size_t)p0.x * 16 + qc];
    float d0 = __int_as_float(p0.y);
    ax = fmaf(v0.x, d0, ax); ay = fmaf(v0.y, d0, ay);
    az = fmaf(v0.z, d0, az); aw = fmaf(v0.w, d0, aw);
    j += 4;
  }
  if (j + qe < end) {
    int2 p = epair[j + qe];
    float4 v = F4[(size_t)p.x * 16 + qc];
    float d = __int_as_float(p.y);
    ax = fmaf(v.x, d, ax); ay = fmaf(v.y, d, ay);
    az = fmaf(v.z, d, az); aw = fmaf(v.w, d, aw);
  }
  // reduce the 4 edge-slot groups (lanes differ in bits 4..5)
  ax += __shfl_xor(ax, 16, 64); ax += __shfl_xor(ax, 32, 64);
  ay += __shfl_xor(ay, 16, 64); ay += __shfl_xor(ay, 32, 64);
  az += __shfl_xor(az, 16, 64); az += __shfl_xor(az, 32, 64);
  aw += __shfl_xor(aw, 16, 64); aw += __shfl_xor(aw, 32, 64);
  if (qe == 0) {
    float dn = dis[node];
    float4 sf = F4[(size_t)node * 16 + qc];
    float4 r;
    r.x = (ax + sf.x * dn) * dn;
    r.y = (ay + sf.y * dn) * dn;
    r.z = (az + sf.z * dn) * dn;
    r.w = (aw + sf.w * dn) * dn;
    reinterpret_cast<float4*>(A)[(size_t)node * 16 + qc] = r;
  }
}

// ---- fused GEMM + bias + relu: F = relu(A @ W + b); 64 rows/block ----
__global__ __launch_bounds__(256) void gemm_bias_relu(const float* __restrict__ X,
    const float* __restrict__ W, const float* __restrict__ b,
    float* __restrict__ F, int N) {
  __shared__ float4 Xs[64][16];
  int col = threadIdx.x & 63, wid = threadIdx.x >> 6;
  float wreg[DIM];
  #pragma unroll
  for (int k = 0; k < DIM; ++k) wreg[k] = W[k * DIM + col];
  float bias = b[col];
  int row0 = blockIdx.x * 64;
  for (int i = threadIdx.x; i < 64 * 16; i += 256) {
    int r = i >> 4, c = i & 15;
    int gr = row0 + r;
    Xs[r][c] = (gr < N) ? reinterpret_cast<const float4*>(X)[(size_t)gr * 16 + c]
                        : make_float4(0.f, 0.f, 0.f, 0.f);
  }
  __syncthreads();
  for (int rr = 0; rr < 16; ++rr) {
    int lr = wid * 16 + rr;
    int row = row0 + lr;
    if (row >= N) break;   // uniform per wave
    float a0 = 0.f, a1 = 0.f, a2 = 0.f, a3 = 0.f;
    #pragma unroll
    for (int kk = 0; kk < 16; ++kk) {
      float4 xv = Xs[lr][kk];
      a0 = fmaf(xv.x, wreg[4 * kk + 0], a0);
      a1 = fmaf(xv.y, wreg[4 * kk + 1], a1);
      a2 = fmaf(xv.z, wreg[4 * kk + 2], a2);
      a3 = fmaf(xv.w, wreg[4 * kk + 3], a3);
    }
    float v = a0 + a1 + a2 + a3 + bias;
    F[(size_t)row * DIM + col] = fmaxf(v, 0.f);
  }
}

// ---- layer-3 fused: y = relu(A@W3+b3) . Wl, block-level graph partials ----
__global__ __launch_bounds__(256) void gemm_dot_kernel(const float* __restrict__ X,
    const float* __restrict__ W, const float* __restrict__ b, const float* __restrict__ Wl,
    const int* __restrict__ batch, float* __restrict__ partial, int N) {
  __shared__ float4 Xs[64][16];
  __shared__ float yv[64];
  __shared__ float gpart[NUM_GRAPHS];
  int col = threadIdx.x & 63, wid = threadIdx.x >> 6;
  float wreg[DIM];
  #pragma unroll
  for (int k = 0; k < DIM; ++k) wreg[k] = W[k * DIM + col];
  float bias = b[col];
  float wl = Wl[col];
  int row0 = blockIdx.x * 64;
  if (threadIdx.x < 64) { yv[threadIdx.x] = 0.f; gpart[threadIdx.x] = 0.f; }
  for (int i = threadIdx.x; i < 64 * 16; i += 256) {
    int r = i >> 4, c = i & 15;
    int gr = row0 + r;
    Xs[r][c] = (gr < N) ? reinterpret_cast<const float4*>(X)[(size_t)gr * 16 + c]
                        : make_float4(0.f, 0.f, 0.f, 0.f);
  }
  __syncthreads();
  for (int rr = 0; rr < 16; ++rr) {
    int lr = wid * 16 + rr;
    int row = row0 + lr;
    if (row >= N) break;   // uniform per wave
    float a0 = 0.f, a1 = 0.f, a2 = 0.f, a3 = 0.f;
    #pragma unroll
    for (int kk = 0; kk < 16; ++kk) {
      float4 xv = Xs[lr][kk];
      a0 = fmaf(xv.x, wreg[4 * kk + 0], a0);
      a1 = fmaf(xv.y, wreg[4 * kk + 1], a1);
      a2 = fmaf(xv.z, wreg[4 * kk + 2], a2);
      a3 = fmaf(xv.w, wreg[4 * kk + 3], a3);
    }
    float v = fmaxf(a0 + a1 + a2 + a3 + bias, 0.f);
    float y = v * wl;
    #pragma unroll
    for (int off = 32; off > 0; off >>= 1) y += __shfl_down(y, off, 64);
    if (col == 0) yv[lr] = y;
  }
  __syncthreads();
  if (threadIdx.x < 64) {
    int row = row0 + threadIdx.x;
    if (row < N) atomicAdd(&gpart[batch[row]], yv[threadIdx.x]);
  }
  __syncthreads();
  if (threadIdx.x < NUM_GRAPHS) {
    int glo = batch[row0];
    int ghi = batch[min(row0 + 63, N - 1)];
    int g = threadIdx.x;
    if (g >= glo && g <= ghi) atomicAdd(&partial[g], gpart[g]);
  }
}

// ---- finalize: out[g] = partial[g]/count_g + bl ----
__global__ void pool_final_kernel(const float* __restrict__ partial, const int* __restrict__ batch,
                                  const float* __restrict__ bl, float* __restrict__ out, int N) {
  int g = threadIdx.x;  // 64 threads
  int lo = 0, hi = N;
  while (lo < hi) { int m = (lo + hi) >> 1; if (batch[m] < g) lo = m + 1; else hi = m; }
  int start = lo;
  hi = N;
  while (lo < hi) { int m = (lo + hi) >> 1; if (batch[m] < g + 1) lo = m + 1; else hi = m; }
  float c = fmaxf((float)(lo - start), 1.f);
  out[g] = partial[g] / c + bl[0];
}

extern "C" void kernel_launch(void* const* d_in, const int* in_sizes, int n_in,
                              void* d_out, int out_size, void* d_ws, size_t ws_size,
                              hipStream_t stream) {
  const float* x     = (const float*)d_in[0];
  const int*   ei    = (const int*)d_in[1];   // int64 in reference, delivered as int32
  const int*   batch = (const int*)d_in[2];
  const float* W1 = (const float*)d_in[3];
  const float* b1 = (const float*)d_in[4];
  const float* W2 = (const float*)d_in[5];
  const float* b2 = (const float*)d_in[6];
  const float* W3 = (const float*)d_in[7];
  const float* b3 = (const float*)d_in[8];
  const float* Wl = (const float*)d_in[9];
  const float* bl = (const float*)d_in[10];
  float* out = (float*)d_out;

  const int* srcp = ei;
  const int* dstp = ei + N_EDGES;

  char* ws = (char*)d_ws;
  size_t off = 0;
  auto alloc = [&](size_t bytes) { void* p = ws + off; off += (bytes + 255) & ~(size_t)255; return p; };
  int*   cnt     = (int*)  alloc((size_t)N_NODES * 4);        // reused as cursor
  float* dis     = (float*)alloc((size_t)N_NODES * 4);
  int*   rowptr  = (int*)  alloc((size_t)(N_NODES + 1) * 4);
  int*   bsum    = (int*)  alloc(64 * 4);
  float* partial = (float*)alloc(NUM_GRAPHS * 4);
  int2*  epair   = (int2*) alloc((size_t)N_EDGES * 8);
  float* bufA    = (float*)alloc((size_t)N_NODES * DIM * 4);
  float* bufB    = (float*)alloc((size_t)N_NODES * DIM * 4);

  const int NB = (N_NODES + 1023) / 1024;  // 49

  // ---- CSR build (edge passes XCD-partitioned by dst range) ----
  zero_kernel<<<(N_NODES + 255) / 256, 256, 0, stream>>>(cnt, partial);
  count_deg_kernel<<<1024, 256, 0, stream>>>(dstp, cnt, N_EDGES);
  scanA_kernel<<<NB, 1024, 0, stream>>>(cnt, rowptr, bsum, dis, N_NODES);
  scanB_kernel<<<1, 64, 0, stream>>>(bsum, rowptr, NB, N_NODES);
  scanC_kernel<<<NB, 1024, 0, stream>>>(rowptr, bsum, cnt, N_NODES);
  fill_kernel<<<1024, 256, 0, stream>>>(srcp, dstp, dis, cnt, epair, N_EDGES);

  // ---- 3 GCN layers ----
  const int GB = (N_NODES + 63) / 64;  // 782
  aggregate_kernel<<<(N_NODES + 3) / 4, 256, 0, stream>>>(x, rowptr, epair, dis, bufA, N_NODES);
  gemm_bias_relu<<<GB, 256, 0, stream>>>(bufA, W1, b1, bufB, N_NODES);
  aggregate_kernel<<<(N_NODES + 3) / 4, 256, 0, stream>>>(bufB, rowptr, epair, dis, bufA, N_NODES);
  gemm_bias_relu<<<GB, 256, 0, stream>>>(bufA, W2, b2, bufB, N_NODES);
  aggregate_kernel<<<(N_NODES + 3) / 4, 256, 0, stream>>>(bufB, rowptr, epair, dis, bufA, N_NODES);
  gemm_dot_kernel<<<GB, 256, 0, stream>>>(bufA, W3, b3, Wl, batch, partial, N_NODES);
  pool_final_kernel<<<1, 64, 0, stream>>>(partial, batch, bl, out, N_NODES);
}

// Round 9
// 231.431 us; speedup vs baseline: 1.0977x; 1.0966x over previous
//
#include <hip/hip_runtime.h>

#define N_NODES 50000
#define N_EDGES 800000
#define DIM 64
#define NUM_GRAPHS 64
#define NPART 8
#define PART_NODES 6250   // N_NODES / NPART exactly

typedef unsigned short u16;
typedef unsigned int u32;

__device__ __forceinline__ u16 bf16_rne(float f) {
  u32 u = __float_as_uint(f);
  u32 r = (u + 0x7fffu + ((u >> 16) & 1u)) >> 16;
  return (u16)r;
}

// ---- zero cnt[N] and partial[G] ----
__global__ void zero_kernel(int* __restrict__ cnt, float* __restrict__ partial) {
  int i = blockIdx.x * blockDim.x + threadIdx.x;
  if (i < N_NODES) cnt[i] = 0;
  if (i < NUM_GRAPHS) partial[i] = 0.f;
}

// ---- convert x (f32) -> xh (bf16), RNE ----
__global__ void convert_kernel(const float* __restrict__ x, u16* __restrict__ xh) {
  int i = blockIdx.x * blockDim.x + threadIdx.x;
  if (i < N_NODES * DIM / 4) {
    float4 v = reinterpret_cast<const float4*>(x)[i];
    ushort4 o;
    o.x = bf16_rne(v.x); o.y = bf16_rne(v.y);
    o.z = bf16_rne(v.z); o.w = bf16_rne(v.w);
    reinterpret_cast<ushort4*>(xh)[i] = o;
  }
}

// ---- degree count, XCD-partitioned ----
__global__ void count_deg_kernel(const int* __restrict__ dst, int* __restrict__ cnt, int E) {
  int p = blockIdx.x & 7;
  int lo = p * PART_NODES, hi = lo + PART_NODES;
  int stride = (gridDim.x >> 3) * blockDim.x;
  for (int e = (blockIdx.x >> 3) * blockDim.x + threadIdx.x; e < E; e += stride) {
    int d = dst[e];
    if (d >= lo && d < hi) atomicAdd(&cnt[d], 1);
  }
}

// ---- scan phase A ----
__global__ void scanA_kernel(const int* __restrict__ cnt, int* __restrict__ rowptr,
                             int* __restrict__ bsum, float* __restrict__ dis, int N) {
  __shared__ int wsum[16];
  int i = blockIdx.x * 1024 + threadIdx.x;
  int lane = threadIdx.x & 63, wid = threadIdx.x >> 6;
  int v = (i < N) ? cnt[i] : 0;
  if (i < N) dis[i] = rsqrtf((float)(v + 1));
  int sv = v;
  #pragma unroll
  for (int off = 1; off < 64; off <<= 1) {
    int t = __shfl_up(sv, off, 64);
    if (lane >= off) sv += t;
  }
  if (lane == 63) wsum[wid] = sv;
  __syncthreads();
  if (wid == 0) {
    int wv = (lane < 16) ? wsum[lane] : 0;
    #pragma unroll
    for (int off = 1; off < 16; off <<= 1) {
      int t = __shfl_up(wv, off, 64);
      if (lane >= off) wv += t;
    }
    if (lane < 16) wsum[lane] = wv;
  }
  __syncthreads();
  if (i < N) rowptr[i] = (wid ? wsum[wid - 1] : 0) + (sv - v);
  if (threadIdx.x == 1023) bsum[blockIdx.x] = wsum[15];
}

// ---- scan phase B ----
__global__ void scanB_kernel(int* __restrict__ bsum, int* __restrict__ rowptr, int nb, int N) {
  int t = threadIdx.x;
  int v = (t < nb) ? bsum[t] : 0;
  #pragma unroll
  for (int off = 1; off < 64; off <<= 1) {
    int u = __shfl_up(v, off, 64);
    if (t >= off) v += u;
  }
  if (t < nb) bsum[t] = v;
  if (t == nb - 1) rowptr[N] = v;
}

// ---- scan phase C ----
__global__ void scanC_kernel(int* __restrict__ rowptr, const int* __restrict__ bsum,
                             int* __restrict__ cursor, int N) {
  int b = blockIdx.x;
  int i = b * 1024 + threadIdx.x;
  if (i < N) {
    int off = b ? bsum[b - 1] : 0;
    int r = rowptr[i] + off;
    rowptr[i] = r;
    cursor[i] = r;
  }
}

// ---- fill CSR, XCD-partitioned; (src, dis[src]) pairs ----
__global__ void fill_kernel(const int* __restrict__ src, const int* __restrict__ dst,
                            const float* __restrict__ dis,
                            int* __restrict__ cursor, int2* __restrict__ epair, int E) {
  int p = blockIdx.x & 7;
  int lo = p * PART_NODES, hi = lo + PART_NODES;
  int stride = (gridDim.x >> 3) * blockDim.x;
  for (int e = (blockIdx.x >> 3) * blockDim.x + threadIdx.x; e < E; e += stride) {
    int d = dst[e];
    if (d >= lo && d < hi) {
      int s = src[e];
      int pos = atomicAdd(&cursor[d], 1);
      epair[pos] = make_int2(s, __float_as_int(dis[s]));
    }
  }
}

#define UNPACK_FMA(q, d)                                              \
  a0 = fmaf(__uint_as_float((q).x << 16), (d), a0);                   \
  a1 = fmaf(__uint_as_float((q).x & 0xffff0000u), (d), a1);           \
  a2 = fmaf(__uint_as_float((q).y << 16), (d), a2);                   \
  a3 = fmaf(__uint_as_float((q).y & 0xffff0000u), (d), a3);           \
  a4 = fmaf(__uint_as_float((q).z << 16), (d), a4);                   \
  a5 = fmaf(__uint_as_float((q).z & 0xffff0000u), (d), a5);           \
  a6 = fmaf(__uint_as_float((q).w << 16), (d), a6);                   \
  a7 = fmaf(__uint_as_float((q).w & 0xffff0000u), (d), a7);

// ---- aggregate (bf16 features): A_i = dis_i*(sum dis_j*F_j + dis_i*F_i) ----
// one wave per node; 8 lanes x 16B cover a 128B bf16 row; 8 edge slots.
__global__ __launch_bounds__(256) void aggregate_kernel(const u16* __restrict__ Fh,
    const int* __restrict__ rowptr, const int2* __restrict__ epair,
    const float* __restrict__ dis, float* __restrict__ A, int N) {
  int node = blockIdx.x * 4 + (threadIdx.x >> 6);
  if (node >= N) return;
  int lane = threadIdx.x & 63;
  int qc = lane & 7;    // 16B chunk index within 128B row (8 bf16 cols)
  int qe = lane >> 3;   // edge slot 0..7
  const uint4* __restrict__ F8 = reinterpret_cast<const uint4*>(Fh);
  int beg = rowptr[node], end = rowptr[node + 1];
  float a0 = 0.f, a1 = 0.f, a2 = 0.f, a3 = 0.f;
  float a4 = 0.f, a5 = 0.f, a6 = 0.f, a7 = 0.f;
  int j = beg;
  for (; j + 16 <= end; j += 16) {
    int2 p0 = epair[j + qe];
    int2 p1 = epair[j + 8 + qe];
    uint4 q0 = F8[(size_t)p0.x * 8 + qc];
    uint4 q1 = F8[(size_t)p1.x * 8 + qc];
    float d0 = __int_as_float(p0.y), d1 = __int_as_float(p1.y);
    UNPACK_FMA(q0, d0)
    UNPACK_FMA(q1, d1)
  }
  if (j + 8 <= end) {
    int2 p0 = epair[j + qe];
    uint4 q0 = F8[(size_t)p0.x * 8 + qc];
    float d0 = __int_as_float(p0.y);
    UNPACK_FMA(q0, d0)
    j += 8;
  }
  if (j + qe < end) {
    int2 p0 = epair[j + qe];
    uint4 q0 = F8[(size_t)p0.x * 8 + qc];
    float d0 = __int_as_float(p0.y);
    UNPACK_FMA(q0, d0)
  }
  // reduce the 8 edge-slot groups (lanes differ in bits 3..5)
  #pragma unroll
  for (int m = 8; m < 64; m <<= 1) {
    a0 += __shfl_xor(a0, m, 64); a1 += __shfl_xor(a1, m, 64);
    a2 += __shfl_xor(a2, m, 64); a3 += __shfl_xor(a3, m, 64);
    a4 += __shfl_xor(a4, m, 64); a5 += __shfl_xor(a5, m, 64);
    a6 += __shfl_xor(a6, m, 64); a7 += __shfl_xor(a7, m, 64);
  }
  if (qe == 0) {
    float dn = dis[node];
    uint4 qs = F8[(size_t)node * 8 + qc];
    float s0 = __uint_as_float(qs.x << 16), s1 = __uint_as_float(qs.x & 0xffff0000u);
    float s2 = __uint_as_float(qs.y << 16), s3 = __uint_as_float(qs.y & 0xffff0000u);
    float s4 = __uint_as_float(qs.z << 16), s5 = __uint_as_float(qs.z & 0xffff0000u);
    float s6 = __uint_as_float(qs.w << 16), s7 = __uint_as_float(qs.w & 0xffff0000u);
    float4 o0, o1;
    o0.x = (a0 + s0 * dn) * dn; o0.y = (a1 + s1 * dn) * dn;
    o0.z = (a2 + s2 * dn) * dn; o0.w = (a3 + s3 * dn) * dn;
    o1.x = (a4 + s4 * dn) * dn; o1.y = (a5 + s5 * dn) * dn;
    o1.z = (a6 + s6 * dn) * dn; o1.w = (a7 + s7 * dn) * dn;
    float4* A4 = reinterpret_cast<float4*>(A + (size_t)node * DIM + qc * 8);
    A4[0] = o0;
    A4[1] = o1;
  }
}

// ---- fused GEMM + bias + relu; writes bf16 for the next aggregate ----
__global__ __launch_bounds__(256) void gemm_bias_relu(const float* __restrict__ X,
    const float* __restrict__ W, const float* __restrict__ b,
    u16* __restrict__ Fh, int N) {
  __shared__ float4 Xs[64][16];
  int col = threadIdx.x & 63, wid = threadIdx.x >> 6;
  float wreg[DIM];
  #pragma unroll
  for (int k = 0; k < DIM; ++k) wreg[k] = W[k * DIM + col];
  float bias = b[col];
  int row0 = blockIdx.x * 64;
  for (int i = threadIdx.x; i < 64 * 16; i += 256) {
    int r = i >> 4, c = i & 15;
    int gr = row0 + r;
    Xs[r][c] = (gr < N) ? reinterpret_cast<const float4*>(X)[(size_t)gr * 16 + c]
                        : make_float4(0.f, 0.f, 0.f, 0.f);
  }
  __syncthreads();
  for (int rr = 0; rr < 16; ++rr) {
    int lr = wid * 16 + rr;
    int row = row0 + lr;
    if (row >= N) break;   // uniform per wave
    float a0 = 0.f, a1 = 0.f, a2 = 0.f, a3 = 0.f;
    #pragma unroll
    for (int kk = 0; kk < 16; ++kk) {
      float4 xv = Xs[lr][kk];
      a0 = fmaf(xv.x, wreg[4 * kk + 0], a0);
      a1 = fmaf(xv.y, wreg[4 * kk + 1], a1);
      a2 = fmaf(xv.z, wreg[4 * kk + 2], a2);
      a3 = fmaf(xv.w, wreg[4 * kk + 3], a3);
    }
    float v = fmaxf(a0 + a1 + a2 + a3 + bias, 0.f);
    Fh[(size_t)row * DIM + col] = bf16_rne(v);
  }
}

// ---- layer-3 fused: y = relu(A@W3+b3) . Wl, block-level graph partials ----
__global__ __launch_bounds__(256) void gemm_dot_kernel(const float* __restrict__ X,
    const float* __restrict__ W, const float* __restrict__ b, const float* __restrict__ Wl,
    const int* __restrict__ batch, float* __restrict__ partial, int N) {
  __shared__ float4 Xs[64][16];
  __shared__ float yv[64];
  __shared__ float gpart[NUM_GRAPHS];
  int col = threadIdx.x & 63, wid = threadIdx.x >> 6;
  float wreg[DIM];
  #pragma unroll
  for (int k = 0; k < DIM; ++k) wreg[k] = W[k * DIM + col];
  float bias = b[col];
  float wl = Wl[col];
  int row0 = blockIdx.x * 64;
  if (threadIdx.x < 64) { yv[threadIdx.x] = 0.f; gpart[threadIdx.x] = 0.f; }
  for (int i = threadIdx.x; i < 64 * 16; i += 256) {
    int r = i >> 4, c = i & 15;
    int gr = row0 + r;
    Xs[r][c] = (gr < N) ? reinterpret_cast<const float4*>(X)[(size_t)gr * 16 + c]
                        : make_float4(0.f, 0.f, 0.f, 0.f);
  }
  __syncthreads();
  for (int rr = 0; rr < 16; ++rr) {
    int lr = wid * 16 + rr;
    int row = row0 + lr;
    if (row >= N) break;   // uniform per wave
    float a0 = 0.f, a1 = 0.f, a2 = 0.f, a3 = 0.f;
    #pragma unroll
    for (int kk = 0; kk < 16; ++kk) {
      float4 xv = Xs[lr][kk];
      a0 = fmaf(xv.x, wreg[4 * kk + 0], a0);
      a1 = fmaf(xv.y, wreg[4 * kk + 1], a1);
      a2 = fmaf(xv.z, wreg[4 * kk + 2], a2);
      a3 = fmaf(xv.w, wreg[4 * kk + 3], a3);
    }
    float v = fmaxf(a0 + a1 + a2 + a3 + bias, 0.f);
    float y = v * wl;
    #pragma unroll
    for (int off = 32; off > 0; off >>= 1) y += __shfl_down(y, off, 64);
    if (col == 0) yv[lr] = y;
  }
  __syncthreads();
  if (threadIdx.x < 64) {
    int row = row0 + threadIdx.x;
    if (row < N) atomicAdd(&gpart[batch[row]], yv[threadIdx.x]);
  }
  __syncthreads();
  if (threadIdx.x < NUM_GRAPHS) {
    int glo = batch[row0];
    int ghi = batch[min(row0 + 63, N - 1)];
    int g = threadIdx.x;
    if (g >= glo && g <= ghi) atomicAdd(&partial[g], gpart[g]);
  }
}

// ---- finalize: out[g] = partial[g]/count_g + bl ----
__global__ void pool_final_kernel(const float* __restrict__ partial, const int* __restrict__ batch,
                                  const float* __restrict__ bl, float* __restrict__ out, int N) {
  int g = threadIdx.x;  // 64 threads
  int lo = 0, hi = N;
  while (lo < hi) { int m = (lo + hi) >> 1; if (batch[m] < g) lo = m + 1; else hi = m; }
  int start = lo;
  hi = N;
  while (lo < hi) { int m = (lo + hi) >> 1; if (batch[m] < g + 1) lo = m + 1; else hi = m; }
  float c = fmaxf((float)(lo - start), 1.f);
  out[g] = partial[g] / c + bl[0];
}

extern "C" void kernel_launch(void* const* d_in, const int* in_sizes, int n_in,
                              void* d_out, int out_size, void* d_ws, size_t ws_size,
                              hipStream_t stream) {
  const float* x     = (const float*)d_in[0];
  const int*   ei    = (const int*)d_in[1];   // int64 in reference, delivered as int32
  const int*   batch = (const int*)d_in[2];
  const float* W1 = (const float*)d_in[3];
  const float* b1 = (const float*)d_in[4];
  const float* W2 = (const float*)d_in[5];
  const float* b2 = (const float*)d_in[6];
  const float* W3 = (const float*)d_in[7];
  const float* b3 = (const float*)d_in[8];
  const float* Wl = (const float*)d_in[9];
  const float* bl = (const float*)d_in[10];
  float* out = (float*)d_out;

  const int* srcp = ei;
  const int* dstp = ei + N_EDGES;

  char* ws = (char*)d_ws;
  size_t off = 0;
  auto alloc = [&](size_t bytes) { void* p = ws + off; off += (bytes + 255) & ~(size_t)255; return p; };
  int*   cnt     = (int*)  alloc((size_t)N_NODES * 4);        // reused as cursor
  float* dis     = (float*)alloc((size_t)N_NODES * 4);
  int*   rowptr  = (int*)  alloc((size_t)(N_NODES + 1) * 4);
  int*   bsum    = (int*)  alloc(64 * 4);
  float* partial = (float*)alloc(NUM_GRAPHS * 4);
  int2*  epair   = (int2*) alloc((size_t)N_EDGES * 8);
  u16*   xh      = (u16*)  alloc((size_t)N_NODES * DIM * 2);  // bf16 feats (also layer-2 out)
  u16*   fh      = (u16*)  alloc((size_t)N_NODES * DIM * 2);  // bf16 layer-1 out
  float* A       = (float*)alloc((size_t)N_NODES * DIM * 4);  // f32 aggregate output

  const int NB = (N_NODES + 1023) / 1024;  // 49

  // ---- CSR build (edge passes XCD-partitioned by dst range) ----
  zero_kernel<<<(N_NODES + 255) / 256, 256, 0, stream>>>(cnt, partial);
  convert_kernel<<<(N_NODES * DIM / 4 + 255) / 256, 256, 0, stream>>>(x, xh);
  count_deg_kernel<<<1024, 256, 0, stream>>>(dstp, cnt, N_EDGES);
  scanA_kernel<<<NB, 1024, 0, stream>>>(cnt, rowptr, bsum, dis, N_NODES);
  scanB_kernel<<<1, 64, 0, stream>>>(bsum, rowptr, NB, N_NODES);
  scanC_kernel<<<NB, 1024, 0, stream>>>(rowptr, bsum, cnt, N_NODES);
  fill_kernel<<<1024, 256, 0, stream>>>(srcp, dstp, dis, cnt, epair, N_EDGES);

  // ---- 3 GCN layers (bf16 gathers, f32 accumulate/GEMM) ----
  const int GB = (N_NODES + 63) / 64;  // 782
  const int AB = (N_NODES + 3) / 4;
  aggregate_kernel<<<AB, 256, 0, stream>>>(xh, rowptr, epair, dis, A, N_NODES);
  gemm_bias_relu<<<GB, 256, 0, stream>>>(A, W1, b1, fh, N_NODES);
  aggregate_kernel<<<AB, 256, 0, stream>>>(fh, rowptr, epair, dis, A, N_NODES);
  gemm_bias_relu<<<GB, 256, 0, stream>>>(A, W2, b2, xh, N_NODES);   // reuse xh
  aggregate_kernel<<<AB, 256, 0, stream>>>(xh, rowptr, epair, dis, A, N_NODES);
  gemm_dot_kernel<<<GB, 256, 0, stream>>>(A, W3, b3, Wl, batch, partial, N_NODES);
  pool_final_kernel<<<1, 64, 0, stream>>>(partial, batch, bl, out, N_NODES);
}